// Round 6
// baseline (6308.340 us; speedup 1.0000x reference)
//
#include <hip/hip_runtime.h>
#include <cmath>

#define B 64
#define S 4096
#define NI 16
#define H 128
#define F 144       // H + NI
#define GB 8        // batches per block
#define NBLK (B / GB)
#define CH 16       // x staging chunk (timesteps)
#define NCH (S / CH)
#define PADH 136    // padded h row length (halves): 68 words -> uniform bank quads
#define PADX 24     // padded x row length (halves)

typedef _Float16 h2   __attribute__((ext_vector_type(2)));
typedef _Float16 h4v  __attribute__((ext_vector_type(4)));
typedef _Float16 h8   __attribute__((ext_vector_type(8)));
typedef float    f4v  __attribute__((ext_vector_type(4)));
typedef unsigned int u32;
typedef unsigned long long u64;
typedef u64 u64x2 __attribute__((ext_vector_type(2)));

__device__ __forceinline__ float rcp_fast(float x) { return __builtin_amdgcn_rcpf(x); }
__device__ __forceinline__ float sigf(float x) {
    return rcp_fast(1.0f + __expf(-x));
}
// tanh(x) = 2*sigmoid(2x) - 1
__device__ __forceinline__ float tanh_fast(float x) {
    const float e = __expf(-2.0f * x);
    return fmaf(2.0f, rcp_fast(1.0f + e), -1.0f);
}
__device__ __forceinline__ h2 cvt2(float a, float b) {
    h2 r; r[0] = (_Float16)a; r[1] = (_Float16)b; return r;
}
// convert 8 consecutive fp32 -> h8
__device__ __forceinline__ h8 cvt8v(const float* p) {
    const float4 f0 = ((const float4*)p)[0];
    const float4 f1 = ((const float4*)p)[1];
    h8 r;
    r[0] = (_Float16)f0.x; r[1] = (_Float16)f0.y;
    r[2] = (_Float16)f0.z; r[3] = (_Float16)f0.w;
    r[4] = (_Float16)f1.x; r[5] = (_Float16)f1.y;
    r[6] = (_Float16)f1.z; r[7] = (_Float16)f1.w;
    return r;
}
__device__ __forceinline__ void pin_f(float& v) { asm volatile("" : "+v"(v)); }
__device__ __forceinline__ void pin_h8(h8& v) {
    u64x2 t = __builtin_bit_cast(u64x2, v);
    u64 a = t[0], b = t[1];
    asm volatile("" : "+v"(a), "+v"(b));
    t[0] = a; t[1] = b;
    v = __builtin_bit_cast(h8, t);
}
__device__ __forceinline__ f4v mfma16(h8 a, h8 b, f4v c) {
    return __builtin_amdgcn_mfma_f32_16x16x32_f16(a, b, c, 0, 0, 0);
}

// ---------------------------------------------------------------------------
// Gate phase: compaction (all 64 lanes take a real (batch,unit) pair via
// __shfl), gate nonlinearity, h-state update, packed h2 write to LDS.
// acc layout (16x16x32 C): row = 4*(lane>>4)+reg = batch-row, col = lane&15.
// Lanes <32 keep their t2=0 tile values; lanes >=32 take the t2=1 tile values
// of lane-32. Compacted unit j = 32w + 16*(lane>=32) + nl, batch = 4*((lane>>4)&1)+rr.
// ---------------------------------------------------------------------------
__device__ __forceinline__ void gates_phase(
    f4v aR0, f4v aR1, f4v aZ0, f4v aZ1,
    f4v aI0, f4v aI1, f4v aH0, f4v aH1,
    float* hp, float bR, float bZ, float bI, float bHN,
    int lane, int jw,
    _Float16 (*dst)[PADH], _Float16 (*dst2)[PADH])
{
    const int srcl = (lane + 32) & 63;     // for hi lanes: lane-32
    const bool hi  = lane >= 32;
    const int batch = 4 * ((lane >> 4) & 1);
#pragma unroll
    for (int rr = 0; rr < 4; rr++) {
        const float tR = __shfl(aR1[rr], srcl);
        const float tZ = __shfl(aZ1[rr], srcl);
        const float tI = __shfl(aI1[rr], srcl);
        const float tH = __shfl(aH1[rr], srcl);
        const float cR = hi ? tR : aR0[rr];
        const float cZ = hi ? tZ : aZ0[rr];
        const float cI = hi ? tI : aI0[rr];
        const float cH = hi ? tH : aH0[rr];

        const float r  = sigf(cR + bR);
        const float z  = sigf(cZ + bZ);
        const float n  = tanh_fast(cI + bI + r * (cH + bHN));
        const float hn = n + z * (hp[rr] - n);
        hp[rr] = hn;

        const float hnN = __shfl(hn, lane ^ 1);   // neighbor unit j^1
        if (!(lane & 1)) {
            const h2 pk = cvt2(hn, hnN);
            const u32 v = __builtin_bit_cast(u32, pk);
            ((u32*)&dst[batch + rr][0])[jw] = v;
            if (dst2) ((u32*)&dst2[batch + rr][0])[jw] = v;
        }
    }
}

// ---------------------------------------------------------------------------
// Batch-in-M MFMA fused 2-layer GRU. NBLK=8 blocks x 512 threads (8 waves).
// Waves 0-3: layer 0; waves 4-7: layer 1 (1-step lag). Each wave owns 32
// units (6 gate-tiles of 16). Per step per wave:
//   gates[16b, units] = x/y . W_ih^T (+) h . W_hh^T  via 16x16x32 MFMAs,
//   A = state rows in padded LDS, B = stationary weight fragments.
// L1's W_ih1 k-chunks 2,3 live in LDS (register budget); x staged per chunk;
// h1 flushed to global in 4-step windows. No flags, no inter-block traffic.
// ---------------------------------------------------------------------------
__global__ __launch_bounds__(512)
void gru_mfma(const float* __restrict__ x,
              const float* __restrict__ w_ih0, const float* __restrict__ w_hh0,
              const float* __restrict__ b_ih0, const float* __restrict__ b_hh0,
              const float* __restrict__ w_ih1, const float* __restrict__ w_hh1,
              const float* __restrict__ b_ih1, const float* __restrict__ b_hh1,
              _Float16* __restrict__ h_out)
{
    __shared__ __align__(16) _Float16 sH0[2][16][PADH];     // 8.5 KB
    __shared__ __align__(16) _Float16 sH1[2][16][PADH];     // 8.5 KB
    __shared__ __align__(16) _Float16 sX[2][CH][16][PADX];  // 24 KB
    __shared__ __align__(16) _Float16 sHo[2][4][GB][PADH];  // 17 KB
    __shared__ __align__(16) _Float16 sWih1[3 * H][72];     // 55.3 KB (k=64..127)

    const int tid   = threadIdx.x;
    const int wave  = tid >> 6;
    const int lane  = tid & 63;
    const int layer = wave >> 2;
    const int w     = wave & 3;
    const int nl    = lane & 15;
    const int q     = lane >> 4;
    const int bg    = blockIdx.x;
    const int hi    = lane >= 32 ? 1 : 0;
    const int j     = 32 * w + 16 * hi + nl;   // compacted unit for gates
    const int jw    = j >> 1;

    // ---------------- stationary weight fragments ----------------
    h8 Bhh[6][4];   // W_hh: T = gate*2 + t2; unit row = gate*H + 32w + 16*t2 + nl
    h8 Bih[6][2];   // L1: W_ih1 k-chunks 0,1. L0: [T][0] = W_ih0 (K=16, q<2).
    {
        const float* Whh = layer ? w_hh1 : w_hh0;
        const float* Wih = layer ? w_ih1 : w_ih0;
#pragma unroll
        for (int T = 0; T < 6; T++) {
            const int un  = 32 * w + 16 * (T & 1) + nl;
            const int row = (T >> 1) * H + un;
#pragma unroll
            for (int kc = 0; kc < 4; kc++)
                Bhh[T][kc] = cvt8v(Whh + (size_t)row * H + 32 * kc + 8 * q);
            if (layer) {
                Bih[T][0] = cvt8v(Wih + (size_t)row * H + 8 * q);
                Bih[T][1] = cvt8v(Wih + (size_t)row * H + 32 + 8 * q);
            } else {
                if (q < 2) Bih[T][0] = cvt8v(Wih + (size_t)row * NI + 8 * q);
                else { h8 z = {}; Bih[T][0] = z; }
                { h8 z = {}; Bih[T][1] = z; }
            }
        }
    }
#pragma unroll
    for (int T = 0; T < 6; T++) {
#pragma unroll
        for (int kc = 0; kc < 4; kc++) pin_h8(Bhh[T][kc]);
        pin_h8(Bih[T][0]); pin_h8(Bih[T][1]);
    }
    // biases for this lane's compacted unit j
    float bR, bZ, bI, bHN;
    {
        const float* bi = layer ? b_ih1 : b_ih0;
        const float* bh = layer ? b_hh1 : b_hh0;
        bR  = bi[j]         + bh[j];
        bZ  = bi[H + j]     + bh[H + j];
        bI  = bi[2 * H + j];
        bHN = bh[2 * H + j];
    }
    pin_f(bR); pin_f(bZ); pin_f(bI); pin_f(bHN);

    // L1 LDS weight byte-offsets (W_ih1 k-chunks 2,3)
    int wOff[6];
#pragma unroll
    for (int T = 0; T < 6; T++) {
        const int row = (T >> 1) * H + 32 * w + 16 * (T & 1) + nl;
        wOff[T] = row * 72 * 2;
    }
    const char* wbase = (const char*)&sWih1[0][0];

    // ---------------- LDS init + prologue staging ----------------
    for (int i = tid; i < 2 * 16 * PADH / 2; i += 512) ((u32*)sH0)[i] = 0;
    for (int i = tid; i < 2 * 16 * PADH / 2; i += 512) ((u32*)sH1)[i] = 0;
    for (int i = tid; i < 2 * CH * 16 * PADX / 2; i += 512) ((u32*)sX)[i] = 0;
    // W_ih1 upper-K half -> LDS (3072 pieces of 8 halves)
    for (int i = tid; i < 3 * H * 8; i += 512) {
        const int row = i >> 3, ko = (i & 7) * 8;
        *(h8*)(&sWih1[row][ko]) = cvt8v(w_ih1 + (size_t)row * H + 64 + ko);
    }
    // x chunk 0 (512 pieces: 16t x 8b x 4 float4)
    {
        const int t = tid >> 5, bb = (tid >> 2) & 7, fp = tid & 3;
        const float4 v = *(const float4*)(x + ((size_t)(bg * GB + bb) * S + t) * NI + 4 * fp);
        h4v p; p[0] = (_Float16)v.x; p[1] = (_Float16)v.y;
               p[2] = (_Float16)v.z; p[3] = (_Float16)v.w;
        *(h4v*)(&sX[0][t][bb][4 * fp]) = p;
    }
    float hp[4] = {0.f, 0.f, 0.f, 0.f};
    __syncthreads();

    // ---------------- main loop ----------------
    for (int s = 0; s <= S; s++) {
        if (layer == 0) {
            if (s < S) {
                const int c = s >> 4, tw = s & 15;
                if (tw == 2) {
                    const int cn = c + 1;
                    if (cn < NCH) {
#pragma unroll
                        for (int e = 0; e < 2; e++) {
                            const int g = tid + 256 * e;
                            const int t = g >> 5, bb = (g >> 2) & 7, fp = g & 3;
                            const float4 v = *(const float4*)(
                                x + ((size_t)(bg * GB + bb) * S + 16 * cn + t) * NI + 4 * fp);
                            h4v p; p[0] = (_Float16)v.x; p[1] = (_Float16)v.y;
                                   p[2] = (_Float16)v.z; p[3] = (_Float16)v.w;
                            *(h4v*)(&sX[cn & 1][t][bb][4 * fp]) = p;
                        }
                    }
                } else if ((s & 3) == 1 && s >= 5) {
                    // flush h1 window W (filled by L1 during steps 4W+1..4W+4)
                    const int W = (s >> 2) - 1, p = W & 1;
#pragma unroll
                    for (int e = 0; e < 2; e++) {
                        const int g = tid + 256 * e;
                        const int t = g >> 7, bb = (g >> 4) & 7, pc = g & 15;
                        const uint4 v = *(const uint4*)(&sHo[p][t][bb][pc * 8]);
                        *(uint4*)(h_out + ((size_t)(bg * GB + bb) * S + 4 * W + t) * H + pc * 8) = v;
                    }
                }

                // A fragments + MFMA: gates = x[s].W_ih0 + h0[s-1].W_hh0
                const _Float16* arow = &sH0[(s + 1) & 1][nl][0];
                h8 Ax;
                if (q < 2) Ax = *(const h8*)(&sX[c & 1][tw][nl][8 * q]);
                else { h8 z = {}; Ax = z; }
                f4v z4 = {0.f, 0.f, 0.f, 0.f};
                f4v aR0 = mfma16(Ax, Bih[0][0], z4), aR1 = mfma16(Ax, Bih[1][0], z4);
                f4v aZ0 = mfma16(Ax, Bih[2][0], z4), aZ1 = mfma16(Ax, Bih[3][0], z4);
                f4v aI0 = mfma16(Ax, Bih[4][0], z4), aI1 = mfma16(Ax, Bih[5][0], z4);
                f4v aH0 = z4, aH1 = z4;
#pragma unroll
                for (int kc = 0; kc < 4; kc++) {
                    const h8 Ah = *(const h8*)(arow + 32 * kc + 8 * q);
                    aR0 = mfma16(Ah, Bhh[0][kc], aR0); aR1 = mfma16(Ah, Bhh[1][kc], aR1);
                    aZ0 = mfma16(Ah, Bhh[2][kc], aZ0); aZ1 = mfma16(Ah, Bhh[3][kc], aZ1);
                    aH0 = mfma16(Ah, Bhh[4][kc], aH0); aH1 = mfma16(Ah, Bhh[5][kc], aH1);
                }
                gates_phase(aR0, aR1, aZ0, aZ1, aI0, aI1, aH0, aH1,
                            hp, bR, bZ, bI, bHN, lane, jw,
                            &sH0[s & 1][0], nullptr);
            }
        } else {
            if (s >= 1) {
                const int t1 = s - 1;
                const _Float16* a1 = &sH1[s & 1][nl][0];        // h1[t1-1]
                const _Float16* a0 = &sH0[(s + 1) & 1][nl][0];  // h0[t1]
                f4v z4 = {0.f, 0.f, 0.f, 0.f};
                f4v aR0 = z4, aR1 = z4, aZ0 = z4, aZ1 = z4;
                f4v aI0 = z4, aI1 = z4, aH0 = z4, aH1 = z4;
#pragma unroll
                for (int kc = 0; kc < 4; kc++) {
                    const h8 A0 = *(const h8*)(a0 + 32 * kc + 8 * q);
                    const h8 A1 = *(const h8*)(a1 + 32 * kc + 8 * q);
                    h8 Bi[6];
                    if (kc < 2) {
#pragma unroll
                        for (int T = 0; T < 6; T++) Bi[T] = Bih[T][kc];
                    } else {
                        const int ko = (32 * (kc - 2) + 8 * q) * 2;
#pragma unroll
                        for (int T = 0; T < 6; T++)
                            Bi[T] = *(const h8*)(wbase + wOff[T] + ko);
                    }
                    aR0 = mfma16(A0, Bi[0], aR0); aR0 = mfma16(A1, Bhh[0][kc], aR0);
                    aR1 = mfma16(A0, Bi[1], aR1); aR1 = mfma16(A1, Bhh[1][kc], aR1);
                    aZ0 = mfma16(A0, Bi[2], aZ0); aZ0 = mfma16(A1, Bhh[2][kc], aZ0);
                    aZ1 = mfma16(A0, Bi[3], aZ1); aZ1 = mfma16(A1, Bhh[3][kc], aZ1);
                    aI0 = mfma16(A0, Bi[4], aI0);
                    aI1 = mfma16(A0, Bi[5], aI1);
                    aH0 = mfma16(A1, Bhh[4][kc], aH0);
                    aH1 = mfma16(A1, Bhh[5][kc], aH1);
                }
                gates_phase(aR0, aR1, aZ0, aZ1, aI0, aI1, aH0, aH1,
                            hp, bR, bZ, bI, bHN, lane, jw,
                            &sH1[(s + 1) & 1][0], &sHo[(t1 >> 2) & 1][t1 & 3][0]);
            }
        }
        __syncthreads();
    }

    // epilogue: flush final window (t1 = 4092..4095)
    if (layer == 0) {
        const int W = (S >> 2) - 1, p = W & 1;
#pragma unroll
        for (int e = 0; e < 2; e++) {
            const int g = tid + 256 * e;
            const int t = g >> 7, bb = (g >> 4) & 7, pc = g & 15;
            const uint4 v = *(const uint4*)(&sHo[p][t][bb][pc * 8]);
            *(uint4*)(h_out + ((size_t)(bg * GB + bb) * S + 4 * W + t) * H + pc * 8) = v;
        }
    }
}

// ---------------------------------------------------------------------------
// MFMA MLP head. 512 blocks x 256 threads (4 independent waves, no barriers).
// ---------------------------------------------------------------------------
__global__ __launch_bounds__(256, 2)
void head_mfma(const _Float16* __restrict__ h1, const float* __restrict__ x,
               const float* __restrict__ w1, const float* __restrict__ b1,
               const float* __restrict__ w2, const float* __restrict__ b2,
               float* __restrict__ inc)
{
    const int wave = threadIdx.x >> 6;
    const int lane = threadIdx.x & 63;
    const int nl   = lane & 15;
    const int q    = lane >> 4;

    h8 Bf[4][5];
    float b1v[4], w2v[4];
#pragma unroll
    for (int t = 0; t < 4; t++) {
        const int n = 16 * t + nl;
        const float* wr = w1 + (size_t)n * F;
#pragma unroll
        for (int c = 0; c < 4; c++)
            Bf[t][c] = cvt8v(wr + 32 * c + 8 * q);
        if (q < 2) Bf[t][4] = cvt8v(wr + 128 + 8 * q);
        else { h8 z = {};
               Bf[t][4] = z; }
        b1v[t] = b1[n];
        w2v[t] = w2[n];
    }
    const float b2v = b2[0];

    const int gw = blockIdx.x * 4 + wave;

    for (int it = 0; it < 8; it++) {
        const int row0 = (gw * 8 + it) * 16;
        const int rm   = row0 + nl;

        const _Float16* hp = h1 + (size_t)rm * H;
        h8 A0 = *(const h8*)(hp + 8 * q);
        h8 A1 = *(const h8*)(hp + 32 + 8 * q);
        h8 A2 = *(const h8*)(hp + 64 + 8 * q);
        h8 A3 = *(const h8*)(hp + 96 + 8 * q);
        h8 A4;
        if (q < 2) A4 = cvt8v(x + (size_t)rm * NI + 8 * q);
        else { h8 z = {}; A4 = z; }

        f4v acc0 = {0.f,0.f,0.f,0.f}, acc1 = {0.f,0.f,0.f,0.f};
        f4v acc2 = {0.f,0.f,0.f,0.f}, acc3 = {0.f,0.f,0.f,0.f};
        acc0 = mfma16(A0, Bf[0][0], acc0); acc1 = mfma16(A0, Bf[1][0], acc1);
        acc2 = mfma16(A0, Bf[2][0], acc2); acc3 = mfma16(A0, Bf[3][0], acc3);
        acc0 = mfma16(A1, Bf[0][1], acc0); acc1 = mfma16(A1, Bf[1][1], acc1);
        acc2 = mfma16(A1, Bf[2][1], acc2); acc3 = mfma16(A1, Bf[3][1], acc3);
        acc0 = mfma16(A2, Bf[0][2], acc0); acc1 = mfma16(A2, Bf[1][2], acc1);
        acc2 = mfma16(A2, Bf[2][2], acc2); acc3 = mfma16(A2, Bf[3][2], acc3);
        acc0 = mfma16(A3, Bf[0][3], acc0); acc1 = mfma16(A3, Bf[1][3], acc1);
        acc2 = mfma16(A3, Bf[2][3], acc2); acc3 = mfma16(A3, Bf[3][3], acc3);
        acc0 = mfma16(A4, Bf[0][4], acc0); acc1 = mfma16(A4, Bf[1][4], acc1);
        acc2 = mfma16(A4, Bf[2][4], acc2); acc3 = mfma16(A4, Bf[3][4], acc3);

        float rs[4];
#pragma unroll
        for (int r = 0; r < 4; r++) {
            rs[r] = fmaxf(acc0[r] + b1v[0], 0.f) * w2v[0]
                  + fmaxf(acc1[r] + b1v[1], 0.f) * w2v[1]
                  + fmaxf(acc2[r] + b1v[2], 0.f) * w2v[2]
                  + fmaxf(acc3[r] + b1v[3], 0.f) * w2v[3];
        }
#pragma unroll
        for (int off = 1; off < 16; off <<= 1) {
#pragma unroll
            for (int r = 0; r < 4; r++)
                rs[r] += __shfl_xor(rs[r], off, 64);
        }
        if (nl == 0) {
            float4 o;
            o.x = tanh_fast(rs[0] + b2v) * 0.125f;
            o.y = tanh_fast(rs[1] + b2v) * 0.125f;
            o.z = tanh_fast(rs[2] + b2v) * 0.125f;
            o.w = tanh_fast(rs[3] + b2v) * 0.125f;
            *(float4*)(inc + row0 + 4 * q) = o;
        }
    }
}

// ---------------------------------------------------------------------------
// Inclusive cumsum over S per batch + initial offset. One block per batch.
// ---------------------------------------------------------------------------
__global__ __launch_bounds__(256)
void cumsum_kernel(const float* __restrict__ inc, const float* __restrict__ init,
                   float* __restrict__ out)
{
    __shared__ float sW[4];
    const int b = blockIdx.x;
    const int tid = threadIdx.x;
    const int lane = tid & 63;
    const int wid = tid >> 6;

    const float* ib = inc + (size_t)b * S;
    float v[16];
#pragma unroll
    for (int i = 0; i < 16; i++) v[i] = ib[tid * 16 + i];

    float run = 0.f;
#pragma unroll
    for (int i = 0; i < 16; i++) { run += v[i]; v[i] = run; }

    float t = run;
#pragma unroll
    for (int off = 1; off < 64; off <<= 1) {
        float u = __shfl_up(t, off, 64);
        if (lane >= off) t += u;
    }
    const float excl = t - run;
    if (lane == 63) sW[wid] = t;
    __syncthreads();

    float wo = 0.f;
#pragma unroll
    for (int w = 0; w < 4; w++) if (w < wid) wo += sW[w];

    const float prefix = wo + excl + init[0];
    float* ob = out + (size_t)b * S;
#pragma unroll
    for (int i = 0; i < 16; i++) ob[tid * 16 + i] = prefix + v[i];
}

// ---------------------------------------------------------------------------
extern "C" void kernel_launch(void* const* d_in, const int* in_sizes, int n_in,
                              void* d_out, int out_size, void* d_ws, size_t ws_size,
                              hipStream_t stream)
{
    (void)in_sizes; (void)n_in; (void)out_size; (void)ws_size;
    const float* x     = (const float*)d_in[0];
    const float* w_ih0 = (const float*)d_in[1];
    const float* w_hh0 = (const float*)d_in[2];
    const float* b_ih0 = (const float*)d_in[3];
    const float* b_hh0 = (const float*)d_in[4];
    const float* w_ih1 = (const float*)d_in[5];
    const float* w_hh1 = (const float*)d_in[6];
    const float* b_ih1 = (const float*)d_in[7];
    const float* b_hh1 = (const float*)d_in[8];
    const float* w1    = (const float*)d_in[9];
    const float* b1    = (const float*)d_in[10];
    const float* w2    = (const float*)d_in[11];
    const float* b2    = (const float*)d_in[12];
    const float* init  = (const float*)d_in[13];
    float* out = (float*)d_out;

    _Float16* hbuf = (_Float16*)d_ws;                               // 64 MB fp16 (h1)
    float* incbuf  = (float*)((char*)d_ws + (size_t)B * S * H * 2); // 1 MB

    hipLaunchKernelGGL(gru_mfma, dim3(NBLK), dim3(512), 0, stream,
                       x, w_ih0, w_hh0, b_ih0, b_hh0,
                       w_ih1, w_hh1, b_ih1, b_hh1, hbuf);
    hipLaunchKernelGGL(head_mfma, dim3(512), dim3(256), 0, stream,
                       hbuf, x, w1, b1, w2, b2, incbuf);
    hipLaunchKernelGGL(cumsum_kernel, dim3(B), dim3(256), 0, stream,
                       incbuf, init, out);
}

// Round 7
// 2504.222 us; speedup vs baseline: 2.5191x; 2.5191x over previous
//
#include <hip/hip_runtime.h>
#include <cmath>

#define B 64
#define S 4096
#define NI 16
#define H 128
#define F 144   // H + NI
#define CH 16   // timesteps per chunk (x staging, y0 handoff, h1 flush)
#define NCH (S / CH)
#define GIP 129 // padded gi row: q-lanes hit banks {0,12,24,4} -> conflict-free

typedef _Float16 h2   __attribute__((ext_vector_type(2)));
typedef _Float16 h4v  __attribute__((ext_vector_type(4)));
typedef _Float16 h8   __attribute__((ext_vector_type(8)));
typedef float    f4v  __attribute__((ext_vector_type(4)));
typedef unsigned long long u64;
typedef u64 u64x2 __attribute__((ext_vector_type(2)));

__device__ __forceinline__ float rcp_fast(float x) { return __builtin_amdgcn_rcpf(x); }
__device__ __forceinline__ float sigf(float x) {
    return rcp_fast(1.0f + __expf(-x));
}
// tanh(x) = 2*sigmoid(2x) - 1
__device__ __forceinline__ float tanh_fast(float x) {
    const float e = __expf(-2.0f * x);
    return fmaf(2.0f, rcp_fast(1.0f + e), -1.0f);
}
// all 4 lanes of each quad end with the 4-lane sum
__device__ __forceinline__ float quad_reduce(float v) {
    int t1 = __builtin_amdgcn_mov_dpp(__float_as_int(v), 0xB1, 0xf, 0xf, true); // xor 1
    v += __int_as_float(t1);
    int t2 = __builtin_amdgcn_mov_dpp(__float_as_int(v), 0x4E, 0xf, 0xf, true); // xor 2
    v += __int_as_float(t2);
    return v;
}
// both lanes of each pair end with the 2-lane sum
__device__ __forceinline__ float pair_reduce(float v) {
    int t1 = __builtin_amdgcn_mov_dpp(__float_as_int(v), 0xB1, 0xf, 0xf, true); // xor 1
    v += __int_as_float(t1);
    return v;
}
__device__ __forceinline__ h2 cvt2(float a, float b) {
    h2 r; r[0] = (_Float16)a; r[1] = (_Float16)b; return r;
}
// convert 8 consecutive fp32 -> 4 packed half2 regs
__device__ __forceinline__ void cvt8(const float* p, h2* w) {
    const float4 f0 = ((const float4*)p)[0];
    const float4 f1 = ((const float4*)p)[1];
    w[0] = cvt2(f0.x, f0.y); w[1] = cvt2(f0.z, f0.w);
    w[2] = cvt2(f1.x, f1.y); w[3] = cvt2(f1.z, f1.w);
}
// convert 8 consecutive fp32 -> h8
__device__ __forceinline__ h8 cvt8v(const float* p) {
    const float4 f0 = ((const float4*)p)[0];
    const float4 f1 = ((const float4*)p)[1];
    h8 r;
    r[0] = (_Float16)f0.x; r[1] = (_Float16)f0.y;
    r[2] = (_Float16)f0.z; r[3] = (_Float16)f0.w;
    r[4] = (_Float16)f1.x; r[5] = (_Float16)f1.y;
    r[6] = (_Float16)f1.z; r[7] = (_Float16)f1.w;
    return r;
}
__device__ __forceinline__ void pin_h2(h2& v) {
    int t = __builtin_bit_cast(int, v);
    asm volatile("" : "+v"(t));
    v = __builtin_bit_cast(h2, t);
}
__device__ __forceinline__ void pin_f(float& v) {
    asm volatile("" : "+v"(v));
}
__device__ __forceinline__ void pin_h8(h8& v) {
    u64x2 t = __builtin_bit_cast(u64x2, v);
    u64 a = t[0], b = t[1];
    asm volatile("" : "+v"(a), "+v"(b));
    t[0] = a; t[1] = b;
    v = __builtin_bit_cast(h8, t);
}
__device__ __forceinline__ f4v mfma16(h8 a, h8 b, f4v c) {
    return __builtin_amdgcn_mfma_f32_16x16x32_f16(a, b, c, 0, 0, 0);
}

// ---- cross-XCD-safe handoff primitives (agent scope -> coherence point) ----
__device__ __forceinline__ void store_y0(void* p, uint2 v) {
    __hip_atomic_store((u64*)p, __builtin_bit_cast(u64, v),
                       __ATOMIC_RELAXED, __HIP_MEMORY_SCOPE_AGENT);
}
__device__ __forceinline__ h8 load_y0_h8(const _Float16* p) {
    u64x2 v;
    v[0] = __hip_atomic_load((const u64*)p,     __ATOMIC_RELAXED, __HIP_MEMORY_SCOPE_AGENT);
    v[1] = __hip_atomic_load((const u64*)p + 1, __ATOMIC_RELAXED, __HIP_MEMORY_SCOPE_AGENT);
    return __builtin_bit_cast(h8, v);
}
// Bounded spin: legitimate waits are short (producer runs ahead); bail after
// ~tens of ms so a stall becomes a wrong answer, not a GPU hang.
__device__ __forceinline__ void wait_flag(int* f) {
    int spins = 0;
    while (__hip_atomic_load(f, __ATOMIC_ACQUIRE, __HIP_MEMORY_SCOPE_AGENT) == 0) {
        __builtin_amdgcn_s_sleep(8);
        if (++spins > (1 << 17)) break;
    }
}
__device__ __forceinline__ void post_flag(int* f) {
    __hip_atomic_store(f, 1, __ATOMIC_RELEASE, __HIP_MEMORY_SCOPE_AGENT);
}

// ---------------------------------------------------------------------------
// Layer-split pipelined GRU (round-3 proven form). 128 blocks x 512 threads.
// blockIdx even: layer-0 producer for batch (blockIdx>>1), quad K-split over
// all 512 threads (x-dots inline, x chunk-staged, y0 flushed via agent stores).
// blockIdx odd : layer-1 consumer:
//   waves 0-3: recurrence ONLY (h . W_hh1, pair K-split) + gates, reading the
//              input projection gi[t] from LDS (3 scalar reads).
//   waves 4-7: MFMA helpers — per 16-step chunk, load next y0 chunk and
//              compute gi = y0 . W_ih1 + biases, and flush h1 chunks.
// All waves execute identical __syncthreads counts (uniform loop).
// ---------------------------------------------------------------------------
__global__ __launch_bounds__(512, 2)
void gru_pipe(const float* __restrict__ x,
              const float* __restrict__ w_ih0, const float* __restrict__ w_hh0,
              const float* __restrict__ b_ih0, const float* __restrict__ b_hh0,
              const float* __restrict__ w_ih1, const float* __restrict__ w_hh1,
              const float* __restrict__ b_ih1, const float* __restrict__ b_hh1,
              _Float16* __restrict__ hbuf, int* __restrict__ flags)
{
    const int tid = threadIdx.x;
    const int b = blockIdx.x >> 1;
    const bool producer = (blockIdx.x & 1) == 0;

    if (producer) {
        // ================= L0 producer =================
        const int j = tid >> 2;     // output unit 0..127
        const int m = tid & 3;      // K quarter

        __shared__ __align__(16) _Float16 sH0[2][H];
        __shared__ __align__(16) _Float16 sX[2][CH][NI];
        __shared__ __align__(16) _Float16 sYo[2][CH][H];

        h2 wh[48];   // [0..15] r, [16..31] z, [32..47] hn   (w_hh0)
        h2 wx[6];    // [0..1] r, [2..3] z, [4..5] in        (w_ih0, quarter of I)
#pragma unroll
        for (int g = 0; g < 3; g++) {
            const float* wr = w_hh0 + (size_t)(g * H + j) * H;
#pragma unroll
            for (int i = 0; i < 4; i++) {
                const int f = (i + m) & 3;
                cvt8(wr + 32 * m + 8 * f, &wh[g * 16 + 4 * i]);
            }
            const float4 wv = *(const float4*)(w_ih0 + (size_t)(g * H + j) * NI + 4 * m);
            wx[g * 2 + 0] = cvt2(wv.x, wv.y);
            wx[g * 2 + 1] = cvt2(wv.z, wv.w);
        }
        float b_r  = b_ih0[j]       + b_hh0[j];
        float b_z  = b_ih0[H + j]   + b_hh0[H + j];
        float b_in = b_ih0[2*H + j];
        float b_hn = b_hh0[2*H + j];
#pragma unroll
        for (int i = 0; i < 48; i++) pin_h2(wh[i]);
#pragma unroll
        for (int i = 0; i < 6; i++) pin_h2(wx[i]);
        pin_f(b_r); pin_f(b_z); pin_f(b_in); pin_f(b_hn);

        const float* xb = x + (size_t)b * S * NI;
        _Float16*    yb = hbuf + (size_t)b * S * H;
        int*         fb = flags + b * NCH;

        float4 xreg = {0.f, 0.f, 0.f, 0.f};
        if (tid < H) sH0[0][tid] = (_Float16)0.0f;
        if (tid < 64) {
            const float4 v = ((const float4*)xb)[tid];
            h4v p; p[0] = (_Float16)v.x; p[1] = (_Float16)v.y;
                   p[2] = (_Float16)v.z; p[3] = (_Float16)v.w;
            ((h4v*)&sX[0][0][0])[tid] = p;
            xreg = ((const float4*)(xb + CH * NI))[tid];
        }
        float hprev = 0.0f;
        __syncthreads();

        for (int k = 0; k <= S; k++) {
            const int cur = k & 1;
            const int c0  = k >> 4;
            const int tw  = k & (CH - 1);

            if (tw == 0 && k >= CH) {
                const int cp = c0 - 1;
                const uint2 v = ((const uint2*)&sYo[cp & 1][0][0])[tid];
                store_y0((char*)(yb + (size_t)cp * CH * H) + 8 * tid, v);
            }
            if (tw == 1 && k >= CH + 1 && tid == 0) post_flag(fb + (c0 - 1));

            if (k < S) {
                if (tw == 0 && tid < 64) {
                    const int cn = c0 + 1;
                    if (cn < NCH) {
                        h4v p; p[0] = (_Float16)xreg.x; p[1] = (_Float16)xreg.y;
                               p[2] = (_Float16)xreg.z; p[3] = (_Float16)xreg.w;
                        ((h4v*)&sX[cn & 1][0][0])[tid] = p;
                        if (cn + 1 < NCH)
                            xreg = ((const float4*)(xb + (size_t)(cn + 1) * CH * NI))[tid];
                    }
                }

                const float4* hv = (const float4*)&sH0[cur][0];
                float ar = 0.f, az = 0.f, ahn = 0.f;
#pragma unroll
                for (int i = 0; i < 4; i++) {
                    const int f = (i + m) & 3;               // addr stagger
                    const float4 q = hv[4 * m + f];
                    const h2 p0 = __builtin_bit_cast(h2, q.x);
                    const h2 p1 = __builtin_bit_cast(h2, q.y);
                    const h2 p2 = __builtin_bit_cast(h2, q.z);
                    const h2 p3 = __builtin_bit_cast(h2, q.w);
                    ar  = __builtin_amdgcn_fdot2(p0, wh[4*i+0],    ar,  false);
                    ar  = __builtin_amdgcn_fdot2(p1, wh[4*i+1],    ar,  false);
                    ar  = __builtin_amdgcn_fdot2(p2, wh[4*i+2],    ar,  false);
                    ar  = __builtin_amdgcn_fdot2(p3, wh[4*i+3],    ar,  false);
                    az  = __builtin_amdgcn_fdot2(p0, wh[16+4*i+0], az,  false);
                    az  = __builtin_amdgcn_fdot2(p1, wh[16+4*i+1], az,  false);
                    az  = __builtin_amdgcn_fdot2(p2, wh[16+4*i+2], az,  false);
                    az  = __builtin_amdgcn_fdot2(p3, wh[16+4*i+3], az,  false);
                    ahn = __builtin_amdgcn_fdot2(p0, wh[32+4*i+0], ahn, false);
                    ahn = __builtin_amdgcn_fdot2(p1, wh[32+4*i+1], ahn, false);
                    ahn = __builtin_amdgcn_fdot2(p2, wh[32+4*i+2], ahn, false);
                    ahn = __builtin_amdgcn_fdot2(p3, wh[32+4*i+3], ahn, false);
                }
                const float2 xq = *(const float2*)&sX[c0 & 1][tw][4 * m];
                const h2 x0 = __builtin_bit_cast(h2, xq.x);
                const h2 x1 = __builtin_bit_cast(h2, xq.y);
                float ain = 0.f;
                ar  = __builtin_amdgcn_fdot2(x0, wx[0], ar,  false);
                ar  = __builtin_amdgcn_fdot2(x1, wx[1], ar,  false);
                az  = __builtin_amdgcn_fdot2(x0, wx[2], az,  false);
                az  = __builtin_amdgcn_fdot2(x1, wx[3], az,  false);
                ain = __builtin_amdgcn_fdot2(x0, wx[4], ain, false);
                ain = __builtin_amdgcn_fdot2(x1, wx[5], ain, false);

                const float vr  = quad_reduce(ar)  + b_r;
                const float vz  = quad_reduce(az)  + b_z;
                const float vin = quad_reduce(ain) + b_in;
                const float vhn = quad_reduce(ahn) + b_hn;

                const float r  = sigf(vr);
                const float z  = sigf(vz);
                const float n  = tanh_fast(vin + r * vhn);
                const float hn = n + z * (hprev - n);
                hprev = hn;
                if (m == 0) {
                    sH0[cur ^ 1][j]     = (_Float16)hn;
                    sYo[c0 & 1][tw][j]  = (_Float16)hn;
                }
            }
            __syncthreads();
        }
        if (tid == 0) post_flag(fb + (NCH - 1));
    } else {
        // ================= L1 consumer: recurrence + MFMA gi-helpers =========
        __shared__ __align__(16) _Float16 sH1[2][H];          // 512 B
        __shared__ __align__(16) float    sGi[2][CH][3][GIP]; // 49.5 KB
        __shared__ __align__(16) _Float16 sHo[2][CH][H];      // 8 KB

        _Float16* yb = hbuf + (size_t)b * S * H;   // y0 in, h1 out (in place)
        int*      fb = flags + b * NCH;

        const bool isRec = (tid < 256);
        const int lane = tid & 63;
        // recurrence mapping (tid < 256)
        const int jr = (tid & 255) >> 1;   // output unit 0..127
        const int mr = tid & 1;            // K half
        // helper mapping (tid >= 256)
        const int wv = (tid >> 6) - 4;     // helper wave 0..3
        const int nl = lane & 15;          // A row (timestep) / B col n
        const int q  = lane >> 4;          // k-group / C row group

        h2 wc[96];          // recurrence: W_hh1, [0..31] r, [32..63] z, [64..95] hn
        float b_hn = 0.0f;
        h8 Bf[6][4];        // helper: stationary W_ih1 fragments
        float bias[6];
        h8 Apre[4];         // helper: prefetched A fragments

        if (isRec) {
#pragma unroll
            for (int g = 0; g < 3; g++) {
#pragma unroll
                for (int i = 0; i < 8; i++) {
                    const int ii = (i + 4 * mr) & 7;     // addr stagger
                    cvt8(w_hh1 + (size_t)(g * H + jr) * H + 64 * mr + 8 * ii,
                         &wc[g * 32 + 4 * i]);
                }
            }
            b_hn = b_hh1[2 * H + jr];
#pragma unroll
            for (int i = 0; i < 96; i++) pin_h2(wc[i]);
            pin_f(b_hn);
            if (tid < H) sH1[0][tid] = (_Float16)0.0f;
        } else {
#pragma unroll
            for (int tt = 0; tt < 6; tt++) {
                const int n = 16 * (wv * 6 + tt) + nl;
                const float* wr = w_ih1 + (size_t)n * H;
#pragma unroll
                for (int kc = 0; kc < 4; kc++)
                    Bf[tt][kc] = cvt8v(wr + 32 * kc + 8 * q);
                bias[tt] = b_ih1[n] + (n < 2 * H ? b_hh1[n] : 0.0f);
            }
#pragma unroll
            for (int tt = 0; tt < 6; tt++) {
#pragma unroll
                for (int kc = 0; kc < 4; kc++) pin_h8(Bf[tt][kc]);
                pin_f(bias[tt]);
            }
            // produce gi for chunk 0
            if (lane == 0) wait_flag(fb + 0);
            {
                const _Float16* yrow = yb + (size_t)nl * H;
                h8 A0c[4];
#pragma unroll
                for (int kc = 0; kc < 4; kc++)
                    A0c[kc] = load_y0_h8(yrow + 32 * kc + 8 * q);
                f4v a0 = {0.f,0.f,0.f,0.f}, a1 = a0, a2 = a0, a3 = a0, a4 = a0, a5 = a0;
#pragma unroll
                for (int kc = 0; kc < 4; kc++) {
                    a0 = mfma16(A0c[kc], Bf[0][kc], a0);
                    a1 = mfma16(A0c[kc], Bf[1][kc], a1);
                    a2 = mfma16(A0c[kc], Bf[2][kc], a2);
                    a3 = mfma16(A0c[kc], Bf[3][kc], a3);
                    a4 = mfma16(A0c[kc], Bf[4][kc], a4);
                    a5 = mfma16(A0c[kc], Bf[5][kc], a5);
                }
                f4v accs[6] = {a0, a1, a2, a3, a4, a5};
                float* gp = &sGi[0][0][0][0];
#pragma unroll
                for (int tt = 0; tt < 6; tt++) {
                    const int n = 16 * (wv * 6 + tt) + nl;
                    const int g = n >> 7, jj = n & 127;
#pragma unroll
                    for (int r = 0; r < 4; r++)
                        gp[((4 * q + r) * 3 + g) * GIP + jj] = accs[tt][r] + bias[tt];
                }
            }
        }
        float hprev = 0.0f;
        __syncthreads();

        for (int t = 0; t < S; t++) {
            const int cur = t & 1;
            const int c   = t >> 4;
            const int tw  = t & (CH - 1);

            if (isRec) {
                const float gr = sGi[c & 1][tw][0][jr];
                const float gz = sGi[c & 1][tw][1][jr];
                const float gn = sGi[c & 1][tw][2][jr];
                const float4* hv = (const float4*)&sH1[cur][0];
                float ar = 0.f, az = 0.f, ahn = 0.f;
#pragma unroll
                for (int i = 0; i < 8; i++) {
                    const int ii = (i + 4 * mr) & 7;     // addr stagger
                    const float4 qv = hv[8 * mr + ii];
                    const h2 p0 = __builtin_bit_cast(h2, qv.x);
                    const h2 p1 = __builtin_bit_cast(h2, qv.y);
                    const h2 p2 = __builtin_bit_cast(h2, qv.z);
                    const h2 p3 = __builtin_bit_cast(h2, qv.w);
                    ar  = __builtin_amdgcn_fdot2(p0, wc[4*i+0],      ar,  false);
                    ar  = __builtin_amdgcn_fdot2(p1, wc[4*i+1],      ar,  false);
                    ar  = __builtin_amdgcn_fdot2(p2, wc[4*i+2],      ar,  false);
                    ar  = __builtin_amdgcn_fdot2(p3, wc[4*i+3],      ar,  false);
                    az  = __builtin_amdgcn_fdot2(p0, wc[32+4*i+0],   az,  false);
                    az  = __builtin_amdgcn_fdot2(p1, wc[32+4*i+1],   az,  false);
                    az  = __builtin_amdgcn_fdot2(p2, wc[32+4*i+2],   az,  false);
                    az  = __builtin_amdgcn_fdot2(p3, wc[32+4*i+3],   az,  false);
                    ahn = __builtin_amdgcn_fdot2(p0, wc[64+4*i+0],   ahn, false);
                    ahn = __builtin_amdgcn_fdot2(p1, wc[64+4*i+1],   ahn, false);
                    ahn = __builtin_amdgcn_fdot2(p2, wc[64+4*i+2],   ahn, false);
                    ahn = __builtin_amdgcn_fdot2(p3, wc[64+4*i+3],   ahn, false);
                }
                const float r  = sigf(pair_reduce(ar) + gr);
                const float z  = sigf(pair_reduce(az) + gz);
                const float n  = tanh_fast(gn + r * (pair_reduce(ahn) + b_hn));
                const float hn = n + z * (hprev - n);
                hprev = hn;
                if (mr == 0) {
                    sH1[cur ^ 1][jr]   = (_Float16)hn;
                    sHo[c & 1][tw][jr] = (_Float16)hn;
                }
            } else {
                if (tw == 0) {
                    // flush h1 chunk c-1 over the consumed y0 (4 KB, 256 thr x 2 uint2)
                    if (c >= 1) {
                        const int cp  = c - 1;
                        const int idx = tid - 256;
                        const uint2 v0 = ((const uint2*)&sHo[cp & 1][0][0])[idx];
                        const uint2 v1 = ((const uint2*)&sHo[cp & 1][0][0])[idx + 256];
                        ((uint2*)(yb + (size_t)cp * CH * H))[idx]       = v0;
                        ((uint2*)(yb + (size_t)cp * CH * H))[idx + 256] = v1;
                    }
                    // start producing gi for chunk c+1: wait + A prefetch
                    if (c + 1 < NCH) {
                        if (lane == 0) wait_flag(fb + (c + 1));
                        const _Float16* yr2 = yb + ((size_t)(c + 1) * CH + nl) * H;
#pragma unroll
                        for (int kc = 0; kc < 4; kc++)
                            Apre[kc] = load_y0_h8(yr2 + 32 * kc + 8 * q);
                    }
                } else if (tw == 1 && c + 1 < NCH) {
                    f4v a0 = {0.f,0.f,0.f,0.f}, a1 = a0, a2 = a0, a3 = a0, a4 = a0, a5 = a0;
#pragma unroll
                    for (int kc = 0; kc < 4; kc++) {
                        a0 = mfma16(Apre[kc], Bf[0][kc], a0);
                        a1 = mfma16(Apre[kc], Bf[1][kc], a1);
                        a2 = mfma16(Apre[kc], Bf[2][kc], a2);
                        a3 = mfma16(Apre[kc], Bf[3][kc], a3);
                        a4 = mfma16(Apre[kc], Bf[4][kc], a4);
                        a5 = mfma16(Apre[kc], Bf[5][kc], a5);
                    }
                    f4v accs[6] = {a0, a1, a2, a3, a4, a5};
                    float* gp = &sGi[(c + 1) & 1][0][0][0];
#pragma unroll
                    for (int tt = 0; tt < 6; tt++) {
                        const int n = 16 * (wv * 6 + tt) + nl;
                        const int g = n >> 7, jj = n & 127;
#pragma unroll
                        for (int r = 0; r < 4; r++)
                            gp[((4 * q + r) * 3 + g) * GIP + jj] = accs[tt][r] + bias[tt];
                    }
                }
            }
            __syncthreads();
        }
        // final h1 chunk flush (helpers; loop's last barrier made sHo visible)
        if (!isRec) {
            const int cp  = NCH - 1;
            const int idx = tid - 256;
            const uint2 v0 = ((const uint2*)&sHo[cp & 1][0][0])[idx];
            const uint2 v1 = ((const uint2*)&sHo[cp & 1][0][0])[idx + 256];
            ((uint2*)(yb + (size_t)cp * CH * H))[idx]       = v0;
            ((uint2*)(yb + (size_t)cp * CH * H))[idx + 256] = v1;
        }
    }
}

// ---------------------------------------------------------------------------
// MFMA MLP head. 512 blocks x 256 threads (4 independent waves, no barriers).
// ---------------------------------------------------------------------------
__global__ __launch_bounds__(256, 2)
void head_mfma(const _Float16* __restrict__ h1, const float* __restrict__ x,
               const float* __restrict__ w1, const float* __restrict__ b1,
               const float* __restrict__ w2, const float* __restrict__ b2,
               float* __restrict__ inc)
{
    const int wave = threadIdx.x >> 6;
    const int lane = threadIdx.x & 63;
    const int nl   = lane & 15;
    const int q    = lane >> 4;

    h8 Bf[4][5];
    float b1v[4], w2v[4];
#pragma unroll
    for (int t = 0; t < 4; t++) {
        const int n = 16 * t + nl;
        const float* wr = w1 + (size_t)n * F;
#pragma unroll
        for (int c = 0; c < 4; c++)
            Bf[t][c] = cvt8v(wr + 32 * c + 8 * q);
        if (q < 2) Bf[t][4] = cvt8v(wr + 128 + 8 * q);
        else { h8 z = {};
               Bf[t][4] = z; }
        b1v[t] = b1[n];
        w2v[t] = w2[n];
    }
    const float b2v = b2[0];

    const int gw = blockIdx.x * 4 + wave;

    for (int it = 0; it < 8; it++) {
        const int row0 = (gw * 8 + it) * 16;
        const int rm   = row0 + nl;

        const _Float16* hp = h1 + (size_t)rm * H;
        h8 A0 = *(const h8*)(hp + 8 * q);
        h8 A1 = *(const h8*)(hp + 32 + 8 * q);
        h8 A2 = *(const h8*)(hp + 64 + 8 * q);
        h8 A3 = *(const h8*)(hp + 96 + 8 * q);
        h8 A4;
        if (q < 2) A4 = cvt8v(x + (size_t)rm * NI + 8 * q);
        else { h8 z = {}; A4 = z; }

        f4v acc0 = {0.f,0.f,0.f,0.f}, acc1 = {0.f,0.f,0.f,0.f};
        f4v acc2 = {0.f,0.f,0.f,0.f}, acc3 = {0.f,0.f,0.f,0.f};
        acc0 = mfma16(A0, Bf[0][0], acc0); acc1 = mfma16(A0, Bf[1][0], acc1);
        acc2 = mfma16(A0, Bf[2][0], acc2); acc3 = mfma16(A0, Bf[3][0], acc3);
        acc0 = mfma16(A1, Bf[0][1], acc0); acc1 = mfma16(A1, Bf[1][1], acc1);
        acc2 = mfma16(A1, Bf[2][1], acc2); acc3 = mfma16(A1, Bf[3][1], acc3);
        acc0 = mfma16(A2, Bf[0][2], acc0); acc1 = mfma16(A2, Bf[1][2], acc1);
        acc2 = mfma16(A2, Bf[2][2], acc2); acc3 = mfma16(A2, Bf[3][2], acc3);
        acc0 = mfma16(A3, Bf[0][3], acc0); acc1 = mfma16(A3, Bf[1][3], acc1);
        acc2 = mfma16(A3, Bf[2][3], acc2); acc3 = mfma16(A3, Bf[3][3], acc3);
        acc0 = mfma16(A4, Bf[0][4], acc0); acc1 = mfma16(A4, Bf[1][4], acc1);
        acc2 = mfma16(A4, Bf[2][4], acc2); acc3 = mfma16(A4, Bf[3][4], acc3);

        float rs[4];
#pragma unroll
        for (int r = 0; r < 4; r++) {
            rs[r] = fmaxf(acc0[r] + b1v[0], 0.f) * w2v[0]
                  + fmaxf(acc1[r] + b1v[1], 0.f) * w2v[1]
                  + fmaxf(acc2[r] + b1v[2], 0.f) * w2v[2]
                  + fmaxf(acc3[r] + b1v[3], 0.f) * w2v[3];
        }
#pragma unroll
        for (int off = 1; off < 16; off <<= 1) {
#pragma unroll
            for (int r = 0; r < 4; r++)
                rs[r] += __shfl_xor(rs[r], off, 64);
        }
        if (nl == 0) {
            float4 o;
            o.x = tanh_fast(rs[0] + b2v) * 0.125f;
            o.y = tanh_fast(rs[1] + b2v) * 0.125f;
            o.z = tanh_fast(rs[2] + b2v) * 0.125f;
            o.w = tanh_fast(rs[3] + b2v) * 0.125f;
            *(float4*)(inc + row0 + 4 * q) = o;
        }
    }
}

// ---------------------------------------------------------------------------
// Inclusive cumsum over S per batch + initial offset. One block per batch.
// ---------------------------------------------------------------------------
__global__ __launch_bounds__(256)
void cumsum_kernel(const float* __restrict__ inc, const float* __restrict__ init,
                   float* __restrict__ out)
{
    __shared__ float sW[4];
    const int b = blockIdx.x;
    const int tid = threadIdx.x;
    const int lane = tid & 63;
    const int wid = tid >> 6;

    const float* ib = inc + (size_t)b * S;
    float v[16];
#pragma unroll
    for (int i = 0; i < 16; i++) v[i] = ib[tid * 16 + i];

    float run = 0.f;
#pragma unroll
    for (int i = 0; i < 16; i++) { run += v[i]; v[i] = run; }

    float t = run;
#pragma unroll
    for (int off = 1; off < 64; off <<= 1) {
        float u = __shfl_up(t, off, 64);
        if (lane >= off) t += u;
    }
    const float excl = t - run;
    if (lane == 63) sW[wid] = t;
    __syncthreads();

    float wo = 0.f;
#pragma unroll
    for (int w = 0; w < 4; w++) if (w < wid) wo += sW[w];

    const float prefix = wo + excl + init[0];
    float* ob = out + (size_t)b * S;
#pragma unroll
    for (int i = 0; i < 16; i++) ob[tid * 16 + i] = prefix + v[i];
}

// ---------------------------------------------------------------------------
extern "C" void kernel_launch(void* const* d_in, const int* in_sizes, int n_in,
                              void* d_out, int out_size, void* d_ws, size_t ws_size,
                              hipStream_t stream)
{
    (void)in_sizes; (void)n_in; (void)out_size; (void)ws_size;
    const float* x     = (const float*)d_in[0];
    const float* w_ih0 = (const float*)d_in[1];
    const float* w_hh0 = (const float*)d_in[2];
    const float* b_ih0 = (const float*)d_in[3];
    const float* b_hh0 = (const float*)d_in[4];
    const float* w_ih1 = (const float*)d_in[5];
    const float* w_hh1 = (const float*)d_in[6];
    const float* b_ih1 = (const float*)d_in[7];
    const float* b_hh1 = (const float*)d_in[8];
    const float* w1    = (const float*)d_in[9];
    const float* b1    = (const float*)d_in[10];
    const float* w2    = (const float*)d_in[11];
    const float* b2    = (const float*)d_in[12];
    const float* init  = (const float*)d_in[13];
    float* out = (float*)d_out;

    _Float16* hbuf = (_Float16*)d_ws;                                   // 64 MB fp16
    float* incbuf  = (float*)((char*)d_ws + (size_t)B * S * H * 2);     // 1 MB
    int* flags     = (int*)((char*)d_ws + (size_t)B * S * H * 2
                                        + (size_t)B * S * 4);           // 64 KB

    hipMemsetAsync(flags, 0, (size_t)B * NCH * sizeof(int), stream);

    hipLaunchKernelGGL(gru_pipe, dim3(2 * B), dim3(512), 0, stream,
                       x, w_ih0, w_hh0, b_ih0, b_hh0,
                       w_ih1, w_hh1, b_ih1, b_hh1, hbuf, flags);
    hipLaunchKernelGGL(head_mfma, dim3(512), dim3(256), 0, stream,
                       hbuf, x, w1, b1, w2, b2, incbuf);
    hipLaunchKernelGGL(cumsum_kernel, dim3(B), dim3(256), 0, stream,
                       incbuf, init, out);
}